// Round 2
// baseline (350.192 us; speedup 1.0000x reference)
//
#include <hip/hip_runtime.h>

// out[n,o] = sum_i x[n,i] * w[o,i] * att[n,i,o] + bias[o]
// N=256, I=1024, O=1024, fp32. HBM-bound on the 1.074 GB attention tensor.
//
// Structure: i-dimension split 8-ways across blocks for occupancy
// (2048 blocks x 4 waves = 32 waves/CU), float4 (16B/lane) nontemporal
// streaming loads of att, partials in d_ws, tiny reduce kernel adds bias.

typedef float f32x4 __attribute__((ext_vector_type(4)));

constexpr int Nn = 256;
constexpr int Ii = 1024;
constexpr int Oo = 1024;
constexpr int ISPLIT = 8;
constexpr int IRANGE = Ii / ISPLIT;   // 128
constexpr int TPB = 256;              // 4 o per thread -> covers O=1024

__global__ __launch_bounds__(TPB)
void attn_partial_kernel(const float* __restrict__ x,
                         const float* __restrict__ att,
                         const float* __restrict__ w,
                         float* __restrict__ partial) {
    __shared__ float xs[IRANGE];

    const int s   = blockIdx.x;   // i-slice; b%8 == s -> one XCD per slice
    const int n   = blockIdx.y;
    const int tid = threadIdx.x;
    const int i0  = s * IRANGE;

    if (tid < IRANGE / 4) {
        reinterpret_cast<f32x4*>(xs)[tid] =
            reinterpret_cast<const f32x4*>(x + (size_t)n * Ii + i0)[tid];
    }
    __syncthreads();

    const int o0 = tid * 4;
    const float* attp = att + ((size_t)n * Ii + i0) * Oo + o0;
    const float* w0p  = w + (size_t)(o0 + 0) * Ii + i0;
    const float* w1p  = w + (size_t)(o0 + 1) * Ii + i0;
    const float* w2p  = w + (size_t)(o0 + 2) * Ii + i0;
    const float* w3p  = w + (size_t)(o0 + 3) * Ii + i0;

    f32x4 acc = {0.f, 0.f, 0.f, 0.f};

#define STEP(k, aV)                                  \
    acc[0] = fmaf(xv[k] * w0[k], aV[0], acc[0]);     \
    acc[1] = fmaf(xv[k] * w1[k], aV[1], acc[1]);     \
    acc[2] = fmaf(xv[k] * w2[k], aV[2], acc[2]);     \
    acc[3] = fmaf(xv[k] * w3[k], aV[3], acc[3]);

    #pragma unroll 2
    for (int i = 0; i < IRANGE; i += 4) {
        // weight: i-contiguous 16B per row, L2-resident (512KB slice per XCD)
        f32x4 w0 = *reinterpret_cast<const f32x4*>(w0p + i);
        f32x4 w1 = *reinterpret_cast<const f32x4*>(w1p + i);
        f32x4 w2 = *reinterpret_cast<const f32x4*>(w2p + i);
        f32x4 w3 = *reinterpret_cast<const f32x4*>(w3p + i);
        // x: LDS broadcast
        f32x4 xv = *reinterpret_cast<const f32x4*>(&xs[i]);
        // attention: the 1.07 GB stream — 16B/lane coalesced, nontemporal
        f32x4 a0 = __builtin_nontemporal_load(
            reinterpret_cast<const f32x4*>(attp + (size_t)(i + 0) * Oo));
        f32x4 a1 = __builtin_nontemporal_load(
            reinterpret_cast<const f32x4*>(attp + (size_t)(i + 1) * Oo));
        f32x4 a2 = __builtin_nontemporal_load(
            reinterpret_cast<const f32x4*>(attp + (size_t)(i + 2) * Oo));
        f32x4 a3 = __builtin_nontemporal_load(
            reinterpret_cast<const f32x4*>(attp + (size_t)(i + 3) * Oo));

        STEP(0, a0)
        STEP(1, a1)
        STEP(2, a2)
        STEP(3, a3)
    }
#undef STEP

    *reinterpret_cast<f32x4*>(partial + ((size_t)s * Nn + n) * Oo + o0) = acc;
}

__global__ __launch_bounds__(TPB)
void attn_reduce_kernel(const float* __restrict__ partial,
                        const float* __restrict__ bias,
                        float* __restrict__ out) {
    const int n   = blockIdx.x;
    const int tid = threadIdx.x;
    const int o0  = tid * 4;

    f32x4 acc = *reinterpret_cast<const f32x4*>(bias + o0);
    #pragma unroll
    for (int s = 0; s < ISPLIT; ++s) {
        f32x4 p = *reinterpret_cast<const f32x4*>(
            partial + ((size_t)s * Nn + n) * Oo + o0);
        acc[0] += p[0]; acc[1] += p[1]; acc[2] += p[2]; acc[3] += p[3];
    }
    *reinterpret_cast<f32x4*>(out + (size_t)n * Oo + o0) = acc;
}

extern "C" void kernel_launch(void* const* d_in, const int* in_sizes, int n_in,
                              void* d_out, int out_size, void* d_ws, size_t ws_size,
                              hipStream_t stream) {
    const float* x    = (const float*)d_in[0];
    const float* att  = (const float*)d_in[1];
    const float* w    = (const float*)d_in[2];
    const float* bias = (const float*)d_in[3];
    float* out        = (float*)d_out;
    float* partial    = (float*)d_ws;   // ISPLIT*Nn*Oo floats = 8 MB

    dim3 grid1(ISPLIT, Nn);   // (8, 256) = 2048 blocks
    attn_partial_kernel<<<grid1, TPB, 0, stream>>>(x, att, w, partial);

    attn_reduce_kernel<<<Nn, TPB, 0, stream>>>(partial, bias, out);
}

// Round 3
// 202.242 us; speedup vs baseline: 1.7315x; 1.7315x over previous
//
#include <hip/hip_runtime.h>

// out[n,o] = sum_i x[n,i] * w[o,i] * att[n,i,o] + bias[o]
// N=256, I=1024, O=1024, fp32. HBM-bound on the 1.074 GB attention tensor.
//
// R3: eliminate the scattered weight reads (the R1/R2 invariant bottleneck
// hypothesis). Pre-transpose w -> wT[i][o] in d_ws, so the main kernel reads
// weight with the same coalesced pattern as att. att uses nontemporal loads
// so the 1 GB stream doesn't evict the L2-resident weight slice.

typedef float f32x4 __attribute__((ext_vector_type(4)));

constexpr int Nn = 256;
constexpr int Ii = 1024;
constexpr int Oo = 1024;
constexpr int ISPLIT = 8;
constexpr int IRANGE = Ii / ISPLIT;   // 128
constexpr int TPB = 256;              // 4 o per thread -> covers O=1024

// ---- w[o][i] -> wT[i][o], 32x32 LDS tiles ----
__global__ __launch_bounds__(256)
void transpose_w_kernel(const float* __restrict__ w, float* __restrict__ wT) {
    __shared__ float tile[32][33];
    const int bi = blockIdx.x * 32;       // i base
    const int bo = blockIdx.y * 32;       // o base
    const int tx = threadIdx.x % 32;
    const int ty = threadIdx.x / 32;      // 0..7
    #pragma unroll
    for (int r = 0; r < 4; ++r)
        tile[ty + 8 * r][tx] = w[(size_t)(bo + ty + 8 * r) * Ii + bi + tx];
    __syncthreads();
    #pragma unroll
    for (int r = 0; r < 4; ++r)
        wT[(size_t)(bi + ty + 8 * r) * Oo + bo + tx] = tile[tx][ty + 8 * r];
}

__global__ __launch_bounds__(TPB)
void attn_partial_kernel(const float* __restrict__ x,
                         const float* __restrict__ att,
                         const float* __restrict__ wT,
                         float* __restrict__ partial) {
    __shared__ float xs[IRANGE];

    const int s   = blockIdx.x;   // i-slice; linear id % 8 == s -> one XCD per slice
    const int n   = blockIdx.y;
    const int tid = threadIdx.x;
    const int i0  = s * IRANGE;

    if (tid < IRANGE / 4) {
        reinterpret_cast<f32x4*>(xs)[tid] =
            reinterpret_cast<const f32x4*>(x + (size_t)n * Ii + i0)[tid];
    }
    __syncthreads();

    const int o0 = tid * 4;
    const float* attp = att + ((size_t)n * Ii + i0) * Oo + o0;
    const float* wtp  = wT + (size_t)i0 * Oo + o0;   // same row-stride pattern as att

    f32x4 acc = {0.f, 0.f, 0.f, 0.f};

#define STEP(k, wV, aV)                                   \
    acc[0] = fmaf(xv[k] * wV[0], aV[0], acc[0]);          \
    acc[1] = fmaf(xv[k] * wV[1], aV[1], acc[1]);          \
    acc[2] = fmaf(xv[k] * wV[2], aV[2], acc[2]);          \
    acc[3] = fmaf(xv[k] * wV[3], aV[3], acc[3]);

    #pragma unroll 2
    for (int i = 0; i < IRANGE; i += 4) {
        // weight: coalesced 16B/lane, L2-resident (512KB i-slice per XCD)
        f32x4 w0 = *reinterpret_cast<const f32x4*>(wtp + (size_t)(i + 0) * Oo);
        f32x4 w1 = *reinterpret_cast<const f32x4*>(wtp + (size_t)(i + 1) * Oo);
        f32x4 w2 = *reinterpret_cast<const f32x4*>(wtp + (size_t)(i + 2) * Oo);
        f32x4 w3 = *reinterpret_cast<const f32x4*>(wtp + (size_t)(i + 3) * Oo);
        // x: LDS broadcast
        f32x4 xv = *reinterpret_cast<const f32x4*>(&xs[i]);
        // attention: the 1.07 GB stream — 16B/lane coalesced, nontemporal
        f32x4 a0 = __builtin_nontemporal_load(
            reinterpret_cast<const f32x4*>(attp + (size_t)(i + 0) * Oo));
        f32x4 a1 = __builtin_nontemporal_load(
            reinterpret_cast<const f32x4*>(attp + (size_t)(i + 1) * Oo));
        f32x4 a2 = __builtin_nontemporal_load(
            reinterpret_cast<const f32x4*>(attp + (size_t)(i + 2) * Oo));
        f32x4 a3 = __builtin_nontemporal_load(
            reinterpret_cast<const f32x4*>(attp + (size_t)(i + 3) * Oo));

        STEP(0, w0, a0)
        STEP(1, w1, a1)
        STEP(2, w2, a2)
        STEP(3, w3, a3)
    }
#undef STEP

    *reinterpret_cast<f32x4*>(partial + ((size_t)s * Nn + n) * Oo + o0) = acc;
}

__global__ __launch_bounds__(TPB)
void attn_reduce_kernel(const float* __restrict__ partial,
                        const float* __restrict__ bias,
                        float* __restrict__ out) {
    const int n   = blockIdx.x;
    const int tid = threadIdx.x;
    const int o0  = tid * 4;

    f32x4 acc = *reinterpret_cast<const f32x4*>(bias + o0);
    #pragma unroll
    for (int s = 0; s < ISPLIT; ++s) {
        f32x4 p = *reinterpret_cast<const f32x4*>(
            partial + ((size_t)s * Nn + n) * Oo + o0);
        acc[0] += p[0]; acc[1] += p[1]; acc[2] += p[2]; acc[3] += p[3];
    }
    *reinterpret_cast<f32x4*>(out + (size_t)n * Oo + o0) = acc;
}

extern "C" void kernel_launch(void* const* d_in, const int* in_sizes, int n_in,
                              void* d_out, int out_size, void* d_ws, size_t ws_size,
                              hipStream_t stream) {
    const float* x    = (const float*)d_in[0];
    const float* att  = (const float*)d_in[1];
    const float* w    = (const float*)d_in[2];
    const float* bias = (const float*)d_in[3];
    float* out        = (float*)d_out;

    // ws layout: [0, 8MB) partials, [8MB, 12MB) wT
    float* partial = (float*)d_ws;                              // ISPLIT*Nn*Oo floats
    float* wT      = (float*)((char*)d_ws + (size_t)ISPLIT * Nn * Oo * sizeof(float));

    dim3 tgrid(Ii / 32, Oo / 32);    // (32, 32)
    transpose_w_kernel<<<tgrid, 256, 0, stream>>>(w, wT);

    dim3 grid1(ISPLIT, Nn);          // (8, 256) = 2048 blocks
    attn_partial_kernel<<<grid1, TPB, 0, stream>>>(x, att, wT, partial);

    attn_reduce_kernel<<<Nn, TPB, 0, stream>>>(partial, bias, out);
}

// Round 4
// 191.544 us; speedup vs baseline: 1.8283x; 1.0559x over previous
//
#include <hip/hip_runtime.h>

// out[n,o] = sum_i x[n,i] * w[o,i] * att[n,i,o] + bias[o]
// N=256, I=1024, O=1024, fp32. HBM-bound on the 1.074 GB attention tensor.
//
// R4: n-batch NB=4 per block. Each wT load is reused for 4 samples ->
// wT L2 traffic 1GB -> 256MB, VMEM instr mix per 16KB att: 32 -> 20 loads.
// Everything else keeps R3's coalesced layout (wT pre-transpose, nt att
// stream, ISPLIT=8 partials + tiny reduce).

typedef float f32x4 __attribute__((ext_vector_type(4)));

constexpr int Nn = 256;
constexpr int Ii = 1024;
constexpr int Oo = 1024;
constexpr int ISPLIT = 8;
constexpr int IRANGE = Ii / ISPLIT;   // 128
constexpr int NB = 4;                 // samples per block
constexpr int TPB = 256;              // 4 o per thread -> covers O=1024

// ---- w[o][i] -> wT[i][o], 32x32 LDS tiles ----
__global__ __launch_bounds__(256)
void transpose_w_kernel(const float* __restrict__ w, float* __restrict__ wT) {
    __shared__ float tile[32][33];
    const int bi = blockIdx.x * 32;
    const int bo = blockIdx.y * 32;
    const int tx = threadIdx.x % 32;
    const int ty = threadIdx.x / 32;
    #pragma unroll
    for (int r = 0; r < 4; ++r)
        tile[ty + 8 * r][tx] = w[(size_t)(bo + ty + 8 * r) * Ii + bi + tx];
    __syncthreads();
    #pragma unroll
    for (int r = 0; r < 4; ++r)
        wT[(size_t)(bi + ty + 8 * r) * Oo + bo + tx] = tile[tx][ty + 8 * r];
}

__global__ __launch_bounds__(TPB)
void attn_partial_kernel(const float* __restrict__ x,
                         const float* __restrict__ att,
                         const float* __restrict__ wT,
                         float* __restrict__ partial) {
    __shared__ float xs4[IRANGE][NB];   // x transposed: one b128 read = 4 samples

    const int s   = blockIdx.x;         // i-slice
    const int ng  = blockIdx.y;         // n-group
    const int tid = threadIdx.x;
    const int i0  = s * IRANGE;
    const int n0  = ng * NB;

    if (tid < IRANGE) {
        #pragma unroll
        for (int j = 0; j < NB; ++j)
            xs4[tid][j] = x[(size_t)(n0 + j) * Ii + i0 + tid];
    }
    __syncthreads();

    const int o0 = tid * 4;
    const float* a0p = att + ((size_t)(n0 + 0) * Ii + i0) * Oo + o0;
    const float* a1p = att + ((size_t)(n0 + 1) * Ii + i0) * Oo + o0;
    const float* a2p = att + ((size_t)(n0 + 2) * Ii + i0) * Oo + o0;
    const float* a3p = att + ((size_t)(n0 + 3) * Ii + i0) * Oo + o0;
    const float* wtp = wT + (size_t)i0 * Oo + o0;

    f32x4 acc0 = {0.f, 0.f, 0.f, 0.f};
    f32x4 acc1 = {0.f, 0.f, 0.f, 0.f};
    f32x4 acc2 = {0.f, 0.f, 0.f, 0.f};
    f32x4 acc3 = {0.f, 0.f, 0.f, 0.f};

#define ROW(ii)                                                              \
    {                                                                        \
        const size_t roff = (size_t)(ii) * Oo;                               \
        f32x4 wv = *reinterpret_cast<const f32x4*>(wtp + roff);              \
        f32x4 xv = *reinterpret_cast<const f32x4*>(&xs4[ii][0]);             \
        f32x4 b0 = __builtin_nontemporal_load(                               \
            reinterpret_cast<const f32x4*>(a0p + roff));                     \
        f32x4 b1 = __builtin_nontemporal_load(                               \
            reinterpret_cast<const f32x4*>(a1p + roff));                     \
        f32x4 b2 = __builtin_nontemporal_load(                               \
            reinterpret_cast<const f32x4*>(a2p + roff));                     \
        f32x4 b3 = __builtin_nontemporal_load(                               \
            reinterpret_cast<const f32x4*>(a3p + roff));                     \
        _Pragma("unroll")                                                    \
        for (int k = 0; k < 4; ++k) {                                        \
            acc0[k] = fmaf(xv[0] * wv[k], b0[k], acc0[k]);                   \
            acc1[k] = fmaf(xv[1] * wv[k], b1[k], acc1[k]);                   \
            acc2[k] = fmaf(xv[2] * wv[k], b2[k], acc2[k]);                   \
            acc3[k] = fmaf(xv[3] * wv[k], b3[k], acc3[k]);                   \
        }                                                                    \
    }

    #pragma unroll 2
    for (int i = 0; i < IRANGE; i += 2) {
        ROW(i + 0)
        ROW(i + 1)
    }
#undef ROW

    float* pp = partial + ((size_t)s * Nn + n0) * Oo + o0;
    *reinterpret_cast<f32x4*>(pp + 0 * (size_t)Oo) = acc0;
    *reinterpret_cast<f32x4*>(pp + 1 * (size_t)Oo) = acc1;
    *reinterpret_cast<f32x4*>(pp + 2 * (size_t)Oo) = acc2;
    *reinterpret_cast<f32x4*>(pp + 3 * (size_t)Oo) = acc3;
}

__global__ __launch_bounds__(TPB)
void attn_reduce_kernel(const float* __restrict__ partial,
                        const float* __restrict__ bias,
                        float* __restrict__ out) {
    const int n   = blockIdx.x;
    const int tid = threadIdx.x;
    const int o0  = tid * 4;

    f32x4 acc = *reinterpret_cast<const f32x4*>(bias + o0);
    #pragma unroll
    for (int s = 0; s < ISPLIT; ++s) {
        f32x4 p = *reinterpret_cast<const f32x4*>(
            partial + ((size_t)s * Nn + n) * Oo + o0);
        acc[0] += p[0]; acc[1] += p[1]; acc[2] += p[2]; acc[3] += p[3];
    }
    *reinterpret_cast<f32x4*>(out + (size_t)n * Oo + o0) = acc;
}

extern "C" void kernel_launch(void* const* d_in, const int* in_sizes, int n_in,
                              void* d_out, int out_size, void* d_ws, size_t ws_size,
                              hipStream_t stream) {
    const float* x    = (const float*)d_in[0];
    const float* att  = (const float*)d_in[1];
    const float* w    = (const float*)d_in[2];
    const float* bias = (const float*)d_in[3];
    float* out        = (float*)d_out;

    // ws layout: [0, 8MB) partials, [8MB, 12MB) wT
    float* partial = (float*)d_ws;
    float* wT      = (float*)((char*)d_ws + (size_t)ISPLIT * Nn * Oo * sizeof(float));

    dim3 tgrid(Ii / 32, Oo / 32);
    transpose_w_kernel<<<tgrid, 256, 0, stream>>>(w, wT);

    dim3 grid1(ISPLIT, Nn / NB);     // (8, 64) = 512 blocks, 2 blocks/CU
    attn_partial_kernel<<<grid1, TPB, 0, stream>>>(x, att, wT, partial);

    attn_reduce_kernel<<<Nn, TPB, 0, stream>>>(partial, bias, out);
}

// Round 5
// 182.635 us; speedup vs baseline: 1.9174x; 1.0488x over previous
//
#include <hip/hip_runtime.h>

// out[n,o] = sum_i x[n,i] * w[o,i] * att[n,i,o] + bias[o]
// N=256, I=1024, O=1024, fp32. HBM-bound on the 1.074 GB attention tensor.
//
// R5: two kernels only. Transpose w -> wT[i][o] (coalesced weight), then one
// fused kernel: block = (o-chunk 128, n-group 4); 8 subgroups x 32 lanes own
// 128-wide i-slices; LDS cross-subgroup reduction + bias in the epilogue.
// Eliminates the 16 MB partial round-trip and the third launch vs R4.

typedef float f32x4 __attribute__((ext_vector_type(4)));

constexpr int Nn = 256;
constexpr int Ii = 1024;
constexpr int Oo = 1024;
constexpr int NB = 4;        // samples per block
constexpr int OCHUNK = 128;  // o per block
constexpr int NSUB = 8;      // i-subgroups per block (32 lanes each)
constexpr int ISUB = Ii / NSUB;   // 128
constexpr int TPB = 256;

// ---- w[o][i] -> wT[i][o], 32x32 LDS tiles ----
__global__ __launch_bounds__(256)
void transpose_w_kernel(const float* __restrict__ w, float* __restrict__ wT) {
    __shared__ float tile[32][33];
    const int bi = blockIdx.x * 32;
    const int bo = blockIdx.y * 32;
    const int tx = threadIdx.x % 32;
    const int ty = threadIdx.x / 32;
    #pragma unroll
    for (int r = 0; r < 4; ++r)
        tile[ty + 8 * r][tx] = w[(size_t)(bo + ty + 8 * r) * Ii + bi + tx];
    __syncthreads();
    #pragma unroll
    for (int r = 0; r < 4; ++r)
        wT[(size_t)(bi + ty + 8 * r) * Oo + bo + tx] = tile[tx][ty + 8 * r];
}

__global__ __launch_bounds__(TPB)
void attn_fused_kernel(const float* __restrict__ x,
                       const float* __restrict__ att,
                       const float* __restrict__ wT,
                       const float* __restrict__ bias,
                       float* __restrict__ out) {
    __shared__ float xs[NB][Ii];               // 16 KB: x rows for the 4 samples
    __shared__ float red[NSUB][NB * OCHUNK];   // 16 KB: per-subgroup partials

    const int ocx = blockIdx.x;                // o-chunk; linear%8==ocx -> XCD
    const int ng  = blockIdx.y;
    const int tid = threadIdx.x;
    const int g   = tid >> 5;                  // subgroup = i-slice owner
    const int t   = tid & 31;
    const int n0  = ng * NB;
    const int oc0 = ocx * OCHUNK;

    // stage x[n0..n0+3][:] -> LDS (coalesced f32x4 per row)
    #pragma unroll
    for (int nb = 0; nb < NB; ++nb)
        reinterpret_cast<f32x4*>(&xs[nb][0])[tid] =
            reinterpret_cast<const f32x4*>(x + (size_t)(n0 + nb) * Ii)[tid];
    __syncthreads();

    const int i0 = g * ISUB;
    const int o0 = oc0 + t * 4;

    const float* a0p = att + ((size_t)(n0 + 0) * Ii + i0) * Oo + o0;
    const float* a1p = att + ((size_t)(n0 + 1) * Ii + i0) * Oo + o0;
    const float* a2p = att + ((size_t)(n0 + 2) * Ii + i0) * Oo + o0;
    const float* a3p = att + ((size_t)(n0 + 3) * Ii + i0) * Oo + o0;
    const float* wtp = wT + (size_t)i0 * Oo + o0;

    f32x4 acc0 = {0.f, 0.f, 0.f, 0.f};
    f32x4 acc1 = {0.f, 0.f, 0.f, 0.f};
    f32x4 acc2 = {0.f, 0.f, 0.f, 0.f};
    f32x4 acc3 = {0.f, 0.f, 0.f, 0.f};

    for (int ii = 0; ii < ISUB; ii += 4) {
        // x values for 4 consecutive i, all 4 samples (LDS broadcast b128)
        f32x4 xv0 = *reinterpret_cast<const f32x4*>(&xs[0][i0 + ii]);
        f32x4 xv1 = *reinterpret_cast<const f32x4*>(&xs[1][i0 + ii]);
        f32x4 xv2 = *reinterpret_cast<const f32x4*>(&xs[2][i0 + ii]);
        f32x4 xv3 = *reinterpret_cast<const f32x4*>(&xs[3][i0 + ii]);
        #pragma unroll
        for (int e = 0; e < 4; ++e) {
            const size_t roff = (size_t)(ii + e) * Oo;
            f32x4 wv = *reinterpret_cast<const f32x4*>(wtp + roff);
            f32x4 b0 = __builtin_nontemporal_load(
                reinterpret_cast<const f32x4*>(a0p + roff));
            f32x4 b1 = __builtin_nontemporal_load(
                reinterpret_cast<const f32x4*>(a1p + roff));
            f32x4 b2 = __builtin_nontemporal_load(
                reinterpret_cast<const f32x4*>(a2p + roff));
            f32x4 b3 = __builtin_nontemporal_load(
                reinterpret_cast<const f32x4*>(a3p + roff));
            #pragma unroll
            for (int k = 0; k < 4; ++k) {
                acc0[k] = fmaf(xv0[e] * wv[k], b0[k], acc0[k]);
                acc1[k] = fmaf(xv1[e] * wv[k], b1[k], acc1[k]);
                acc2[k] = fmaf(xv2[e] * wv[k], b2[k], acc2[k]);
                acc3[k] = fmaf(xv3[e] * wv[k], b3[k], acc3[k]);
            }
        }
    }

    // per-subgroup partials -> LDS
    *reinterpret_cast<f32x4*>(&red[g][0 * OCHUNK + t * 4]) = acc0;
    *reinterpret_cast<f32x4*>(&red[g][1 * OCHUNK + t * 4]) = acc1;
    *reinterpret_cast<f32x4*>(&red[g][2 * OCHUNK + t * 4]) = acc2;
    *reinterpret_cast<f32x4*>(&red[g][3 * OCHUNK + t * 4]) = acc3;
    __syncthreads();

    // cross-subgroup reduce: 512 outputs, 2 per thread (float2)
    {
        const int fl = tid * 2;          // nb*128 + ol, pair stays within nb
        const int nb = fl >> 7;
        const int ol = fl & 127;
        float sx = 0.f, sy = 0.f;
        #pragma unroll
        for (int g2 = 0; g2 < NSUB; ++g2) {
            const float* rp = &red[g2][fl];
            sx += rp[0];
            sy += rp[1];
        }
        sx += bias[oc0 + ol];
        sy += bias[oc0 + ol + 1];
        float2 res = {sx, sy};
        *reinterpret_cast<float2*>(out + (size_t)(n0 + nb) * Oo + oc0 + ol) = res;
    }
}

extern "C" void kernel_launch(void* const* d_in, const int* in_sizes, int n_in,
                              void* d_out, int out_size, void* d_ws, size_t ws_size,
                              hipStream_t stream) {
    const float* x    = (const float*)d_in[0];
    const float* att  = (const float*)d_in[1];
    const float* w    = (const float*)d_in[2];
    const float* bias = (const float*)d_in[3];
    float* out        = (float*)d_out;
    float* wT         = (float*)d_ws;    // 4 MB

    dim3 tgrid(Ii / 32, Oo / 32);
    transpose_w_kernel<<<tgrid, 256, 0, stream>>>(w, wT);

    dim3 grid(Oo / OCHUNK, Nn / NB);     // (8, 64) = 512 blocks
    attn_fused_kernel<<<grid, TPB, 0, stream>>>(x, att, wT, bias, out);
}